// Round 3
// baseline (565.549 us; speedup 1.0000x reference)
//
#include <hip/hip_runtime.h>
#include <hip/hip_bf16.h>

typedef __attribute__((ext_vector_type(8))) short short8;
typedef __attribute__((ext_vector_type(4))) short short4v;
typedef __attribute__((ext_vector_type(4))) float f32x4;

#define NR 8192
#define LOG2E 1.4426950408889634f

__device__ __forceinline__ short f2bf(float f) {
  return __builtin_bit_cast(short, __float2bfloat16(f));
}

// ---------------------------------------------------------------------------
// K0: pack adj (int32 0/1, 256 MB) -> bitmask (8 MB). Pure streaming, no
// dependent work -> HBM-saturating (~42 us). Each thread: 32 adj entries ->
// one uint32. Per-lane 128 B contiguous; every 64B line fully consumed.
// ---------------------------------------------------------------------------
__global__ __launch_bounds__(256) void k_pack(const int* __restrict__ adj,
                                              unsigned* __restrict__ mask) {
  size_t gid = (size_t)blockIdx.x * 256 + threadIdx.x;  // word index, 2M total
  const int4* p = (const int4*)&adj[gid * 32];
  unsigned m = 0;
#pragma unroll
  for (int c = 0; c < 8; ++c) {
    int4 v = p[c];
    m |= (unsigned)(v.x > 0) << (c * 4 + 0);
    m |= (unsigned)(v.y > 0) << (c * 4 + 1);
    m |= (unsigned)(v.z > 0) << (c * 4 + 2);
    m |= (unsigned)(v.w > 0) << (c * 4 + 3);
  }
  mask[gid] = m;
}

// ---------------------------------------------------------------------------
// K1: HT = (x @ W)^T in bf16, fused s,t epilogue.
// 128 blocks x 64 rows. 16x16x32 bf16 MFMA; A[m=lane&15][k=q*8+j],
// B[k][n=lane&15], C col=lane&15, row=q*4+reg (verified m89/m91).
// ---------------------------------------------------------------------------
__global__ __launch_bounds__(256) void k_gemm_h(const float* __restrict__ x,
                                                const float* __restrict__ W,
                                                const float* __restrict__ a,
                                                short* __restrict__ HT,
                                                float* __restrict__ sv,
                                                float* __restrict__ tv) {
  __shared__ short WT[128][136];  // pad 8 shorts -> 2-way alias (free, m136)
  const int tid = threadIdx.x;
  const int w = tid >> 6;
  const int L = tid & 63;
  const int lm = L & 15;
  const int q = L >> 4;
  const int i0 = blockIdx.x * 64;

  f32x4 acc[8];
#pragma unroll
  for (int nn = 0; nn < 8; ++nn) acc[nn] = (f32x4){0.f, 0.f, 0.f, 0.f};

  for (int kc = 0; kc < 256; kc += 128) {
    if (kc) __syncthreads();
#pragma unroll
    for (int p = 0; p < 16; ++p) {
      int idx = p * 256 + tid;  // 0..4095
      int k = idx >> 5;         // 0..127
      int f4 = (idx & 31) * 4;
      float4 v = *(const float4*)&W[(kc + k) * 128 + f4];
      WT[f4 + 0][k] = f2bf(v.x);
      WT[f4 + 1][k] = f2bf(v.y);
      WT[f4 + 2][k] = f2bf(v.z);
      WT[f4 + 3][k] = f2bf(v.w);
    }
    __syncthreads();
#pragma unroll
    for (int ks = 0; ks < 4; ++ks) {
      int row = i0 + 16 * w + lm;
      const float* xp = &x[(size_t)row * 256 + kc + ks * 32 + q * 8];
      float4 xa = *(const float4*)xp;
      float4 xb = *(const float4*)(xp + 4);
      short8 af;
      af[0] = f2bf(xa.x); af[1] = f2bf(xa.y); af[2] = f2bf(xa.z); af[3] = f2bf(xa.w);
      af[4] = f2bf(xb.x); af[5] = f2bf(xb.y); af[6] = f2bf(xb.z); af[7] = f2bf(xb.w);
#pragma unroll
      for (int nn = 0; nn < 8; ++nn) {
        short8 bf = *(const short8*)&WT[nn * 16 + lm][ks * 32 + q * 8];
        acc[nn] = __builtin_amdgcn_mfma_f32_16x16x32_bf16(af, bf, acc[nn], 0, 0, 0);
      }
    }
  }

  const int ib = i0 + 16 * w + 4 * q;
  float a1v[8], a2v[8];
#pragma unroll
  for (int nn = 0; nn < 8; ++nn) {
    a1v[nn] = a[nn * 16 + lm];
    a2v[nn] = a[128 + nn * 16 + lm];
  }
  float sr[4] = {0.f, 0.f, 0.f, 0.f};
  float tr[4] = {0.f, 0.f, 0.f, 0.f};
#pragma unroll
  for (int nn = 0; nn < 8; ++nn) {
    int f = nn * 16 + lm;
    short4v o;
    o[0] = f2bf(acc[nn][0]);
    o[1] = f2bf(acc[nn][1]);
    o[2] = f2bf(acc[nn][2]);
    o[3] = f2bf(acc[nn][3]);
    *(short4v*)&HT[(size_t)f * NR + ib] = o;
#pragma unroll
    for (int r = 0; r < 4; ++r) {
      sr[r] += acc[nn][r] * a1v[nn];
      tr[r] += acc[nn][r] * a2v[nn];
    }
  }
#pragma unroll
  for (int d = 1; d < 16; d <<= 1) {
#pragma unroll
    for (int r = 0; r < 4; ++r) {
      sr[r] += __shfl_xor(sr[r], d);
      tr[r] += __shfl_xor(tr[r], d);
    }
  }
  if (lm == 0) {
#pragma unroll
    for (int r = 0; r < 4; ++r) {
      sv[ib + r] = sr[r] * LOG2E;
      tv[ib + r] = tr[r] * LOG2E;
    }
  }
}

// ---------------------------------------------------------------------------
// K3: flash-GAT using the bitmask. No LDS, no barriers. Block = 128 i-rows,
// 4 waves x 32 rows (2x16). Mask: one uint4 per row per 4 j-iterations,
// broadcast across the 4 q-lanes (L3/L2-resident, ~200 cyc — trivially
// hidden). HT B-frags straight from L2-resident global. P built in A-frag
// register layout.
// ---------------------------------------------------------------------------
__global__ __launch_bounds__(256, 4) void k_flash(const unsigned* __restrict__ mask,
                                                  const short* __restrict__ HT,
                                                  const float* __restrict__ sv,
                                                  const float* __restrict__ tv,
                                                  float* __restrict__ part,
                                                  float* __restrict__ lpart,
                                                  int S) {
  const int tid = threadIdx.x;
  const int w = tid >> 6;
  const int L = tid & 63;
  const int lm = L & 15;
  const int q = L >> 4;
  const int sp = blockIdx.x >> 6;  // 64 i-tiles fixed
  const int it = blockIdx.x & 63;
  const int i0 = it * 128;

  const int row0 = i0 + 32 * w + lm;
  const int row1 = row0 + 16;
  const float s0 = sv[row0];
  const float s1 = sv[row1];

  f32x4 acc[2][8];
#pragma unroll
  for (int mm = 0; mm < 2; ++mm)
#pragma unroll
    for (int nn = 0; nn < 8; ++nn) acc[mm][nn] = (f32x4){0.f, 0.f, 0.f, 0.f};
  float l0 = 0.f, l1 = 0.f;

  const int JR = NR / S;
  const int j0 = sp * JR;
  const int ngroups = JR >> 7;  // 4-iteration groups (128 j each)
  const int w0base = row0 * 256 + (j0 >> 5);  // mask words per row = 256
  const int w1base = row1 * 256 + (j0 >> 5);

#pragma unroll 2
  for (int jg = 0; jg < ngroups; ++jg) {
    uint4 mw0 = *(const uint4*)&mask[w0base + jg * 4];
    uint4 mw1 = *(const uint4*)&mask[w1base + jg * 4];
    unsigned mwa0[4] = {mw0.x, mw0.y, mw0.z, mw0.w};
    unsigned mwa1[4] = {mw1.x, mw1.y, mw1.z, mw1.w};
#pragma unroll
    for (int jk = 0; jk < 4; ++jk) {
      const int jb = j0 + (jg * 4 + jk) * 32 + q * 8;
      float4 t0 = *(const float4*)&tv[jb];
      float4 t1 = *(const float4*)&tv[jb + 4];
      short8 bf[8];
#pragma unroll
      for (int nn = 0; nn < 8; ++nn)
        bf[nn] = *(const short8*)&HT[(size_t)(nn * 16 + lm) * NR + jb];

      const unsigned b0 = (mwa0[jk] >> (q * 8)) & 0xffu;
      const unsigned b1 = (mwa1[jk] >> (q * 8)) & 0xffu;
      float tvl[8] = {t0.x, t0.y, t0.z, t0.w, t1.x, t1.y, t1.z, t1.w};
      short8 p0, p1;
#pragma unroll
      for (int e = 0; e < 8; ++e) {
        // logits pre-scaled by log2e; lrelu(v) = max(v, 0.2v)
        float v0 = s0 + tvl[e];
        float e0 = fmaxf(v0, 0.2f * v0);
        float pp0 = (b0 & (1u << e)) ? __builtin_amdgcn_exp2f(e0) : 0.f;
        l0 += pp0;
        p0[e] = f2bf(pp0);
        float v1 = s1 + tvl[e];
        float e1 = fmaxf(v1, 0.2f * v1);
        float pp1 = (b1 & (1u << e)) ? __builtin_amdgcn_exp2f(e1) : 0.f;
        l1 += pp1;
        p1[e] = f2bf(pp1);
      }
#pragma unroll
      for (int nn = 0; nn < 8; ++nn) {
        acc[0][nn] = __builtin_amdgcn_mfma_f32_16x16x32_bf16(p0, bf[nn], acc[0][nn], 0, 0, 0);
        acc[1][nn] = __builtin_amdgcn_mfma_f32_16x16x32_bf16(p1, bf[nn], acc[1][nn], 0, 0, 0);
      }
    }
  }

  // unnormalized numerator partials
  float* ps = part + (size_t)sp * (NR * 128);
#pragma unroll
  for (int mm = 0; mm < 2; ++mm) {
    int ib = i0 + 32 * w + 16 * mm + 4 * q;
#pragma unroll
    for (int nn = 0; nn < 8; ++nn) {
      int f = nn * 16 + lm;
#pragma unroll
      for (int r = 0; r < 4; ++r) ps[(size_t)(ib + r) * 128 + f] = acc[mm][nn][r];
    }
  }
  // denominator: reduce the 4 q-replicas of each row
  l0 += __shfl_xor(l0, 16);
  l0 += __shfl_xor(l0, 32);
  l1 += __shfl_xor(l1, 16);
  l1 += __shfl_xor(l1, 32);
  if (q == 0) {
    lpart[sp * NR + row0] = l0;
    lpart[sp * NR + row1] = l1;
  }
}

// ---------------------------------------------------------------------------
// K4: out[i][f] = sum_sp part / sum_sp lpart   (float4 vectorized)
// ---------------------------------------------------------------------------
__global__ __launch_bounds__(256) void k_reduce(const float* __restrict__ part,
                                                const float* __restrict__ lpart,
                                                float* __restrict__ out, int S) {
  int idx4 = blockIdx.x * 256 + threadIdx.x;
  int idx = idx4 * 4;  // i*128+f
  int i = idx >> 7;
  float4 sum = {0.f, 0.f, 0.f, 0.f};
  for (int sp = 0; sp < S; ++sp) {
    float4 v = *(const float4*)&part[(size_t)sp * (NR * 128) + idx];
    sum.x += v.x; sum.y += v.y; sum.z += v.z; sum.w += v.w;
  }
  float l = 0.f;
  for (int sp = 0; sp < S; ++sp) l += lpart[sp * NR + i];
  float inv = (l > 0.f) ? 1.f / l : 0.f;
  float4 o = {sum.x * inv, sum.y * inv, sum.z * inv, sum.w * inv};
  *(float4*)&out[idx] = o;
}

extern "C" void kernel_launch(void* const* d_in, const int* in_sizes, int n_in,
                              void* d_out, int out_size, void* d_ws, size_t ws_size,
                              hipStream_t stream) {
  const float* x = (const float*)d_in[0];    // 8192 x 256 fp32
  const int* adj = (const int*)d_in[1];      // 8192 x 8192 int32
  const float* W = (const float*)d_in[2];    // 256 x 128 fp32
  const float* a = (const float*)d_in[3];    // 256 x 1 fp32
  float* out = (float*)d_out;                // 8192 x 128 fp32

  char* ws = (char*)d_ws;
  short* HT = (short*)(ws + 0);              // 2 MB  bf16 h^T [128][8192]
  float* sv = (float*)(ws + 2097152);        // 32 KB
  float* tv = (float*)(ws + 2129920);        // 32 KB
  float* lpart = (float*)(ws + 2162688);     // <= 16*32 KB = 512 KB
  unsigned* mask = (unsigned*)(ws + 2686976);  // 8 MB bitmask [8192][256 words]
  float* part = (float*)(ws + 11075584);     // S * 4 MB

  int S = 16;  // j-splits: 1024 blocks -> 4 blocks/CU
  while (S > 1 && (size_t)11075584 + (size_t)S * 4194304 > ws_size) S >>= 1;

  hipLaunchKernelGGL(k_pack, dim3((NR * NR / 32) / 256), dim3(256), 0, stream, adj, mask);
  hipLaunchKernelGGL(k_gemm_h, dim3(128), dim3(256), 0, stream, x, W, a, HT, sv, tv);
  hipLaunchKernelGGL(k_flash, dim3(64 * S), dim3(256), 0, stream, mask, HT, sv, tv,
                     part, lpart, S);
  hipLaunchKernelGGL(k_reduce, dim3((NR * 128) / 1024), dim3(256), 0, stream, part,
                     lpart, out, S);
}

// Round 4
// 469.094 us; speedup vs baseline: 1.2056x; 1.2056x over previous
//
#include <hip/hip_runtime.h>
#include <hip/hip_bf16.h>

typedef __attribute__((ext_vector_type(8))) short short8;
typedef __attribute__((ext_vector_type(4))) short short4v;
typedef __attribute__((ext_vector_type(4))) float f32x4;

#define NR 8192
#define LOG2E 1.4426950408889634f

__device__ __forceinline__ short f2bf(float f) {
  return __builtin_bit_cast(short, __float2bfloat16(f));
}

// ---------------------------------------------------------------------------
// K0: pack adj (int32 0/1, 256 MB) -> bitmask (8 MB). Pure streaming,
// dependence-free -> HBM-saturating (~42 us).
// ---------------------------------------------------------------------------
__global__ __launch_bounds__(256) void k_pack(const int* __restrict__ adj,
                                              unsigned* __restrict__ mask) {
  size_t gid = (size_t)blockIdx.x * 256 + threadIdx.x;  // word index, 2M total
  const int4* p = (const int4*)&adj[gid * 32];
  unsigned m = 0;
#pragma unroll
  for (int c = 0; c < 8; ++c) {
    int4 v = p[c];
    m |= (unsigned)(v.x > 0) << (c * 4 + 0);
    m |= (unsigned)(v.y > 0) << (c * 4 + 1);
    m |= (unsigned)(v.z > 0) << (c * 4 + 2);
    m |= (unsigned)(v.w > 0) << (c * 4 + 3);
  }
  mask[gid] = m;
}

// ---------------------------------------------------------------------------
// K1: HT = (x @ W)^T in bf16, fused s,t epilogue. (unchanged, ~10 us)
// ---------------------------------------------------------------------------
__global__ __launch_bounds__(256) void k_gemm_h(const float* __restrict__ x,
                                                const float* __restrict__ W,
                                                const float* __restrict__ a,
                                                short* __restrict__ HT,
                                                float* __restrict__ sv,
                                                float* __restrict__ tv) {
  __shared__ short WT[128][136];  // pad 8 shorts -> 2-way alias (free, m136)
  const int tid = threadIdx.x;
  const int w = tid >> 6;
  const int L = tid & 63;
  const int lm = L & 15;
  const int q = L >> 4;
  const int i0 = blockIdx.x * 64;

  f32x4 acc[8];
#pragma unroll
  for (int nn = 0; nn < 8; ++nn) acc[nn] = (f32x4){0.f, 0.f, 0.f, 0.f};

  for (int kc = 0; kc < 256; kc += 128) {
    if (kc) __syncthreads();
#pragma unroll
    for (int p = 0; p < 16; ++p) {
      int idx = p * 256 + tid;  // 0..4095
      int k = idx >> 5;         // 0..127
      int f4 = (idx & 31) * 4;
      float4 v = *(const float4*)&W[(kc + k) * 128 + f4];
      WT[f4 + 0][k] = f2bf(v.x);
      WT[f4 + 1][k] = f2bf(v.y);
      WT[f4 + 2][k] = f2bf(v.z);
      WT[f4 + 3][k] = f2bf(v.w);
    }
    __syncthreads();
#pragma unroll
    for (int ks = 0; ks < 4; ++ks) {
      int row = i0 + 16 * w + lm;
      const float* xp = &x[(size_t)row * 256 + kc + ks * 32 + q * 8];
      float4 xa = *(const float4*)xp;
      float4 xb = *(const float4*)(xp + 4);
      short8 af;
      af[0] = f2bf(xa.x); af[1] = f2bf(xa.y); af[2] = f2bf(xa.z); af[3] = f2bf(xa.w);
      af[4] = f2bf(xb.x); af[5] = f2bf(xb.y); af[6] = f2bf(xb.z); af[7] = f2bf(xb.w);
#pragma unroll
      for (int nn = 0; nn < 8; ++nn) {
        short8 bf = *(const short8*)&WT[nn * 16 + lm][ks * 32 + q * 8];
        acc[nn] = __builtin_amdgcn_mfma_f32_16x16x32_bf16(af, bf, acc[nn], 0, 0, 0);
      }
    }
  }

  const int ib = i0 + 16 * w + 4 * q;
  float a1v[8], a2v[8];
#pragma unroll
  for (int nn = 0; nn < 8; ++nn) {
    a1v[nn] = a[nn * 16 + lm];
    a2v[nn] = a[128 + nn * 16 + lm];
  }
  float sr[4] = {0.f, 0.f, 0.f, 0.f};
  float tr[4] = {0.f, 0.f, 0.f, 0.f};
#pragma unroll
  for (int nn = 0; nn < 8; ++nn) {
    int f = nn * 16 + lm;
    short4v o;
    o[0] = f2bf(acc[nn][0]);
    o[1] = f2bf(acc[nn][1]);
    o[2] = f2bf(acc[nn][2]);
    o[3] = f2bf(acc[nn][3]);
    *(short4v*)&HT[(size_t)f * NR + ib] = o;
#pragma unroll
    for (int r = 0; r < 4; ++r) {
      sr[r] += acc[nn][r] * a1v[nn];
      tr[r] += acc[nn][r] * a2v[nn];
    }
  }
#pragma unroll
  for (int d = 1; d < 16; d <<= 1) {
#pragma unroll
    for (int r = 0; r < 4; ++r) {
      sr[r] += __shfl_xor(sr[r], d);
      tr[r] += __shfl_xor(tr[r], d);
    }
  }
  if (lm == 0) {
#pragma unroll
    for (int r = 0; r < 4; ++r) {
      sv[ib + r] = sr[r] * LOG2E;
      tv[ib + r] = tr[r] * LOG2E;
    }
  }
}

// ---------------------------------------------------------------------------
// K3: flash-GAT using the bitmask. Block = 128 i-rows, 4 waves x 32 rows.
// Mask/HT/tv loaded from L2-resident global, no barriers in the main loop.
// Epilogue: acc -> wave-private LDS -> wave-contiguous float4 stores (1 KB
// per store instruction, full lines -> no partial-line RMW amplification).
// __launch_bounds__(256,2): unified reg budget 256/wave so the compiler can
// keep a full iteration of loads in flight (round-3 was starved at 64 VGPR).
// ---------------------------------------------------------------------------
__global__ __launch_bounds__(256, 2) void k_flash(const unsigned* __restrict__ mask,
                                                  const short* __restrict__ HT,
                                                  const float* __restrict__ sv,
                                                  const float* __restrict__ tv,
                                                  float* __restrict__ part,
                                                  float* __restrict__ lpart,
                                                  int S) {
  __shared__ float eps[4][32 * 128];  // 64 KB, 16 KB per wave (wave-private)
  const int tid = threadIdx.x;
  const int w = tid >> 6;
  const int L = tid & 63;
  const int lm = L & 15;
  const int q = L >> 4;
  const int nit = 64;              // i-tiles
  const int sp = blockIdx.x / nit;
  const int it = blockIdx.x % nit;
  const int i0 = it * 128;

  const int row0 = i0 + 32 * w + lm;
  const int row1 = row0 + 16;
  const float s0 = sv[row0];
  const float s1 = sv[row1];

  f32x4 acc[2][8];
#pragma unroll
  for (int mm = 0; mm < 2; ++mm)
#pragma unroll
    for (int nn = 0; nn < 8; ++nn) acc[mm][nn] = (f32x4){0.f, 0.f, 0.f, 0.f};
  float l0 = 0.f, l1 = 0.f;

  const int JR = NR / S;
  const int j0 = sp * JR;
  const int ngroups = JR >> 7;               // 128 j per group
  const int w0base = row0 * 256 + (j0 >> 5);  // 256 mask words per row
  const int w1base = row1 * 256 + (j0 >> 5);

  for (int jg = 0; jg < ngroups; ++jg) {
    uint4 mw0 = *(const uint4*)&mask[w0base + jg * 4];
    uint4 mw1 = *(const uint4*)&mask[w1base + jg * 4];
    unsigned mwa0[4] = {mw0.x, mw0.y, mw0.z, mw0.w};
    unsigned mwa1[4] = {mw1.x, mw1.y, mw1.z, mw1.w};
#pragma unroll
    for (int jk = 0; jk < 4; ++jk) {
      const int jb = j0 + (jg * 4 + jk) * 32 + q * 8;
      float4 t0 = *(const float4*)&tv[jb];
      float4 t1 = *(const float4*)&tv[jb + 4];
      short8 bf[8];
#pragma unroll
      for (int nn = 0; nn < 8; ++nn)
        bf[nn] = *(const short8*)&HT[(size_t)(nn * 16 + lm) * NR + jb];

      const unsigned b0 = (mwa0[jk] >> (q * 8)) & 0xffu;
      const unsigned b1 = (mwa1[jk] >> (q * 8)) & 0xffu;
      float tvl[8] = {t0.x, t0.y, t0.z, t0.w, t1.x, t1.y, t1.z, t1.w};
      short8 p0, p1;
#pragma unroll
      for (int e = 0; e < 8; ++e) {
        // logits pre-scaled by log2e; lrelu(v) = max(v, 0.2v)
        float v0 = s0 + tvl[e];
        float e0 = fmaxf(v0, 0.2f * v0);
        float pp0 = (b0 & (1u << e)) ? __builtin_amdgcn_exp2f(e0) : 0.f;
        l0 += pp0;
        p0[e] = f2bf(pp0);
        float v1 = s1 + tvl[e];
        float e1 = fmaxf(v1, 0.2f * v1);
        float pp1 = (b1 & (1u << e)) ? __builtin_amdgcn_exp2f(e1) : 0.f;
        l1 += pp1;
        p1[e] = f2bf(pp1);
      }
#pragma unroll
      for (int nn = 0; nn < 8; ++nn) {
        acc[0][nn] = __builtin_amdgcn_mfma_f32_16x16x32_bf16(p0, bf[nn], acc[0][nn], 0, 0, 0);
        acc[1][nn] = __builtin_amdgcn_mfma_f32_16x16x32_bf16(p1, bf[nn], acc[1][nn], 0, 0, 0);
      }
    }
  }

  // ---- epilogue: wave-private LDS transpose -> contiguous float4 stores ----
  float* my = eps[w];
#pragma unroll
  for (int mm = 0; mm < 2; ++mm)
#pragma unroll
    for (int nn = 0; nn < 8; ++nn)
#pragma unroll
      for (int r = 0; r < 4; ++r)
        my[(16 * mm + 4 * q + r) * 128 + nn * 16 + lm] = acc[mm][nn][r];
  // wave's 32 rows are contiguous in part: rows i0+32w .. +31
  float* ps = part + ((size_t)sp * NR + i0 + 32 * w) * 128;
#pragma unroll
  for (int c = 0; c < 16; ++c) {
    float4 v = *(float4*)&my[(c * 64 + L) * 4];
    *(float4*)&ps[(size_t)(c * 64 + L) * 4] = v;
  }

  // denominator: reduce the 4 q-replicas of each row
  l0 += __shfl_xor(l0, 16);
  l0 += __shfl_xor(l0, 32);
  l1 += __shfl_xor(l1, 16);
  l1 += __shfl_xor(l1, 32);
  if (q == 0) {
    lpart[sp * NR + row0] = l0;
    lpart[sp * NR + row1] = l1;
  }
}

// ---------------------------------------------------------------------------
// K4: out[i][f] = sum_sp part / sum_sp lpart   (float4 vectorized)
// ---------------------------------------------------------------------------
__global__ __launch_bounds__(256) void k_reduce(const float* __restrict__ part,
                                                const float* __restrict__ lpart,
                                                float* __restrict__ out, int S) {
  int idx4 = blockIdx.x * 256 + threadIdx.x;
  int idx = idx4 * 4;  // i*128+f
  int i = idx >> 7;
  float4 sum = {0.f, 0.f, 0.f, 0.f};
  for (int sp = 0; sp < S; ++sp) {
    float4 v = *(const float4*)&part[(size_t)sp * (NR * 128) + idx];
    sum.x += v.x; sum.y += v.y; sum.z += v.z; sum.w += v.w;
  }
  float l = 0.f;
  for (int sp = 0; sp < S; ++sp) l += lpart[sp * NR + i];
  float inv = (l > 0.f) ? 1.f / l : 0.f;
  float4 o = {sum.x * inv, sum.y * inv, sum.z * inv, sum.w * inv};
  *(float4*)&out[idx] = o;
}

extern "C" void kernel_launch(void* const* d_in, const int* in_sizes, int n_in,
                              void* d_out, int out_size, void* d_ws, size_t ws_size,
                              hipStream_t stream) {
  const float* x = (const float*)d_in[0];    // 8192 x 256 fp32
  const int* adj = (const int*)d_in[1];      // 8192 x 8192 int32
  const float* W = (const float*)d_in[2];    // 256 x 128 fp32
  const float* a = (const float*)d_in[3];    // 256 x 1 fp32
  float* out = (float*)d_out;                // 8192 x 128 fp32

  char* ws = (char*)d_ws;
  short* HT = (short*)(ws + 0);              // 2 MB  bf16 h^T [128][8192]
  float* sv = (float*)(ws + 2097152);        // 32 KB
  float* tv = (float*)(ws + 2129920);        // 32 KB
  float* lpart = (float*)(ws + 2162688);     // <= 16*32 KB = 512 KB
  unsigned* mask = (unsigned*)(ws + 2686976);  // 8 MB bitmask [8192][256 words]
  float* part = (float*)(ws + 11075584);     // S * 4 MB

  int S = 8;  // j-splits: 512 blocks x 4 waves = 2048 waves = 8 waves/CU
  while (S > 1 && (size_t)11075584 + (size_t)S * 4194304 > ws_size) S >>= 1;

  hipLaunchKernelGGL(k_pack, dim3((NR * NR / 32) / 256), dim3(256), 0, stream, adj, mask);
  hipLaunchKernelGGL(k_gemm_h, dim3(128), dim3(256), 0, stream, x, W, a, HT, sv, tv);
  hipLaunchKernelGGL(k_flash, dim3(64 * S), dim3(256), 0, stream, mask, HT, sv, tv,
                     part, lpart, S);
  hipLaunchKernelGGL(k_reduce, dim3((NR * 128) / 1024), dim3(256), 0, stream, part,
                     lpart, out, S);
}